// Round 1
// baseline (114.641 us; speedup 1.0000x reference)
//
#include <hip/hip_runtime.h>
#include <hip/hip_bf16.h>
#include <cstdint>
#include <cstddef>

// BesselKANLayer: y[b,o] = sum_{i,d} bessel_d(tanh(x[b,i])) * C[i,o,d]
// b0 == 1 folded into bias[o] = sum_i C[i,o,0]; GEMM over K = 3*1024.
// A [8192][3072] bf16: A[b][(d-1)*1024 + i] = b_d(tanh(x[b,i])), d=1..3
// Bt [1024][3072] bf16: Bt[o][(d-1)*1024 + i] = C[i][o][d]

#define BATCH   8192
#define IN_DIM  1024
#define OUT_DIM 1024
#define KDIM    3072

typedef __attribute__((ext_vector_type(4))) float f32x4;
typedef __attribute__((ext_vector_type(8))) short bf16x8;

static __device__ __forceinline__ short f2bf(float f) {
    // round-to-nearest-even f32 -> bf16 (finite inputs only)
    uint32_t u = __float_as_uint(f);
    u += 0x7fffu + ((u >> 16) & 1u);
    return (short)(u >> 16);
}

// ---------------- prep: basis matrix A ----------------
__global__ __launch_bounds__(256) void prep_basis(const float* __restrict__ x,
                                                  short* __restrict__ A) {
    int idx = blockIdx.x * 256 + threadIdx.x;   // over BATCH*IN_DIM/4
    int b = idx >> 8;                            // 256 threads-groups of 4 cover 1024
    int i = (idx & 255) << 2;
    const float4 xv = *reinterpret_cast<const float4*>(&x[(size_t)b * IN_DIM + i]);
    float xs[4] = {xv.x, xv.y, xv.z, xv.w};
    short o1[4], o2[4], o3[4];
#pragma unroll
    for (int j = 0; j < 4; ++j) {
        float t  = tanhf(xs[j]);
        float b1 = t + 1.0f;
        float b2 = 3.0f * t * b1 + 1.0f;
        float b3 = 5.0f * t * b2 + b1;
        o1[j] = f2bf(b1); o2[j] = f2bf(b2); o3[j] = f2bf(b3);
    }
    short* row = A + (size_t)b * KDIM;
    *reinterpret_cast<short4*>(&row[i])              = make_short4(o1[0], o1[1], o1[2], o1[3]);
    *reinterpret_cast<short4*>(&row[IN_DIM + i])     = make_short4(o2[0], o2[1], o2[2], o2[3]);
    *reinterpret_cast<short4*>(&row[2 * IN_DIM + i]) = make_short4(o3[0], o3[1], o3[2], o3[3]);
}

// ---------------- prep: transposed coeffs Bt ----------------
__global__ __launch_bounds__(256) void prep_coeffs(const float* __restrict__ C,
                                                   short* __restrict__ Bt) {
    __shared__ short tile[3][32][33];  // +1 pad: conflict-free transposed reads
    const int i0 = blockIdx.x * 32;
    const int o0 = blockIdx.y * 32;
    const int t  = threadIdx.x;
    const int lo = t & 31;   // o within tile (read phase)
    const int li = t >> 5;   // 0..7
#pragma unroll
    for (int r = 0; r < 4; ++r) {
        int i = li + r * 8;
        const float4 c4 = *reinterpret_cast<const float4*>(
            &C[((size_t)(i0 + i) * OUT_DIM + (o0 + lo)) * 4]);
        tile[0][i][lo] = f2bf(c4.y);
        tile[1][i][lo] = f2bf(c4.z);
        tile[2][i][lo] = f2bf(c4.w);
    }
    __syncthreads();
#pragma unroll
    for (int r = 0; r < 4; ++r) {
        int o = (t >> 5) + r * 8;
        int i = t & 31;
#pragma unroll
        for (int d = 0; d < 3; ++d)
            Bt[(size_t)(o0 + o) * KDIM + d * IN_DIM + (i0 + i)] = tile[d][i][o];
    }
}

// ---------------- prep: bias[o] = sum_i C[i][o][0] ----------------
__global__ __launch_bounds__(256) void prep_bias(const float* __restrict__ C,
                                                 float* __restrict__ bias) {
    __shared__ float red[16][17];
    const int t  = threadIdx.x;
    const int ol = t & 15;
    const int il = t >> 4;   // 0..15
    const int o  = blockIdx.x * 16 + ol;
    float s = 0.0f;
    for (int i = il; i < IN_DIM; i += 16)
        s += C[((size_t)i * OUT_DIM + o) * 4];
    red[il][ol] = s;
    __syncthreads();
    if (t < 16) {
        float acc = 0.0f;
#pragma unroll
        for (int k = 0; k < 16; ++k) acc += red[k][t];
        bias[blockIdx.x * 16 + t] = acc;
    }
}

// ---------------- GEMM: out = A * Bt^T + bias ----------------
// 128x128 tile, BK=64, 4 waves (2x2), each wave 64x64 via 4x4 of 16x16x32 MFMA
__global__ __launch_bounds__(256, 2) void gemm_kan(
    const short* __restrict__ A,     // [BATCH][KDIM]
    const short* __restrict__ Bt,    // [OUT_DIM][KDIM]
    const float* __restrict__ bias,  // [OUT_DIM]
    float* __restrict__ out)         // [BATCH][OUT_DIM]
{
    __shared__ short As[128 * 64];
    __shared__ short Bs[128 * 64];

    const int tid  = threadIdx.x;
    const int lane = tid & 63;
    const int wid  = tid >> 6;
    const int wr   = wid >> 1;   // wave row (0..1)
    const int wc   = wid & 1;    // wave col (0..1)
    const int brow = blockIdx.y * 128;
    const int bcol = blockIdx.x * 128;

    f32x4 acc[4][4];
#pragma unroll
    for (int ni = 0; ni < 4; ++ni) {
        float bv = bias[bcol + wc * 64 + ni * 16 + (lane & 15)];
#pragma unroll
        for (int mi = 0; mi < 4; ++mi)
            acc[mi][ni] = (f32x4){bv, bv, bv, bv};
    }

    // staging: 256 threads x 16B = 4096B/instr; tile = 128 rows x 128B
    const int srow = tid >> 3;        // 0..31
    const int scol = (tid & 7) * 8;   // k-element offset
    const short* gA = A  + (size_t)(brow + srow) * KDIM + scol;
    const short* gB = Bt + (size_t)(bcol + srow) * KDIM + scol;
    short* lA = As + tid * 8;  // linear: (srow*64 + scol) == tid*8
    short* lB = Bs + tid * 8;

    for (int kt = 0; kt < KDIM; kt += 64) {
#pragma unroll
        for (int s = 0; s < 4; ++s) {
            __builtin_amdgcn_global_load_lds(
                (const __attribute__((address_space(1))) void*)(gA + (size_t)s * 32 * KDIM + kt),
                (__attribute__((address_space(3))) void*)(lA + s * 32 * 64), 16, 0, 0);
            __builtin_amdgcn_global_load_lds(
                (const __attribute__((address_space(1))) void*)(gB + (size_t)s * 32 * KDIM + kt),
                (__attribute__((address_space(3))) void*)(lB + s * 32 * 64), 16, 0, 0);
        }
        __syncthreads();   // compiler emits vmcnt(0) drain before barrier
#pragma unroll
        for (int kk = 0; kk < 2; ++kk) {
            bf16x8 af[4], bfr[4];
#pragma unroll
            for (int mi = 0; mi < 4; ++mi)
                af[mi] = *reinterpret_cast<const bf16x8*>(
                    &As[(wr * 64 + mi * 16 + (lane & 15)) * 64 + kk * 32 + (lane >> 4) * 8]);
#pragma unroll
            for (int ni = 0; ni < 4; ++ni)
                bfr[ni] = *reinterpret_cast<const bf16x8*>(
                    &Bs[(wc * 64 + ni * 16 + (lane & 15)) * 64 + kk * 32 + (lane >> 4) * 8]);
#pragma unroll
            for (int mi = 0; mi < 4; ++mi)
#pragma unroll
                for (int ni = 0; ni < 4; ++ni)
                    acc[mi][ni] = __builtin_amdgcn_mfma_f32_16x16x32_bf16(
                        af[mi], bfr[ni], acc[mi][ni], 0, 0, 0);
        }
        __syncthreads();
    }

    // epilogue: C/D layout col = lane&15, row = (lane>>4)*4 + reg
#pragma unroll
    for (int mi = 0; mi < 4; ++mi) {
#pragma unroll
        for (int r = 0; r < 4; ++r) {
            int row = brow + wr * 64 + mi * 16 + (lane >> 4) * 4 + r;
            float* orow = out + (size_t)row * OUT_DIM + bcol + wc * 64 + (lane & 15);
#pragma unroll
            for (int ni = 0; ni < 4; ++ni)
                orow[ni * 16] = acc[mi][ni][r];
        }
    }
}

extern "C" void kernel_launch(void* const* d_in, const int* in_sizes, int n_in,
                              void* d_out, int out_size, void* d_ws, size_t ws_size,
                              hipStream_t stream) {
    (void)in_sizes; (void)n_in; (void)out_size; (void)ws_size;
    const float* x      = (const float*)d_in[0];
    const float* coeffs = (const float*)d_in[1];
    float* out = (float*)d_out;

    char* ws = (char*)d_ws;
    short* A    = (short*)ws;                                        // 48 MB
    short* Bt   = (short*)(ws + (size_t)BATCH * KDIM * 2);           // 6 MB
    float* bias = (float*)(ws + (size_t)BATCH * KDIM * 2
                              + (size_t)OUT_DIM * KDIM * 2);         // 4 KB

    hipLaunchKernelGGL(prep_basis, dim3(BATCH * IN_DIM / 4 / 256), dim3(256), 0, stream,
                       x, A);
    hipLaunchKernelGGL(prep_coeffs, dim3(IN_DIM / 32, OUT_DIM / 32), dim3(256), 0, stream,
                       coeffs, Bt);
    hipLaunchKernelGGL(prep_bias, dim3(OUT_DIM / 16), dim3(256), 0, stream,
                       coeffs, bias);
    hipLaunchKernelGGL(gemm_kan, dim3(OUT_DIM / 128, BATCH / 128), dim3(256), 0, stream,
                       A, Bt, bias, out);
}

// Round 2
// 78.590 us; speedup vs baseline: 1.4587x; 1.4587x over previous
//
#include <hip/hip_runtime.h>
#include <hip/hip_bf16.h>
#include <cstdint>
#include <cstddef>

// BesselKANLayer: y[b,o] = sum_{i,d} bessel_d(tanh(x[b,i])) * C[i,o,d]
// b0 == 1 folded into bias[o] = sum_i C[i,o,0]; GEMM over K = 3*1024.
// GEMM: BM=256 BN=128 BK=64, 512 thr (8 waves 4Mx2N, per-wave 64x64),
// triple-buffered LDS (144KB) + counted vmcnt(6) pipeline + XOR bank swizzle.

#define BATCH   8192
#define IN_DIM  1024
#define OUT_DIM 1024
#define KDIM    3072
#define NT      48            // KDIM/64 K-tiles
#define BM      256
#define BN      128
#define LDS_TILE 24576        // shorts per buffer: A 256*64=16384 + B 128*64=8192

typedef __attribute__((ext_vector_type(4))) float f32x4;
typedef __attribute__((ext_vector_type(8))) short bf16x8;

static __device__ __forceinline__ short f2bf(float f) {
    uint32_t u = __float_as_uint(f);
    u += 0x7fffu + ((u >> 16) & 1u);
    return (short)(u >> 16);
}

// ---------------- prep: basis matrix A [8192][3072] bf16 ----------------
__global__ __launch_bounds__(256) void prep_basis(const float* __restrict__ x,
                                                  short* __restrict__ A) {
    int idx = blockIdx.x * 256 + threadIdx.x;
    int b = idx >> 8;
    int i = (idx & 255) << 2;
    const float4 xv = *reinterpret_cast<const float4*>(&x[(size_t)b * IN_DIM + i]);
    float xs[4] = {xv.x, xv.y, xv.z, xv.w};
    short o1[4], o2[4], o3[4];
#pragma unroll
    for (int j = 0; j < 4; ++j) {
        float t  = tanhf(xs[j]);
        float b1 = t + 1.0f;
        float b2 = 3.0f * t * b1 + 1.0f;
        float b3 = 5.0f * t * b2 + b1;
        o1[j] = f2bf(b1); o2[j] = f2bf(b2); o3[j] = f2bf(b3);
    }
    short* row = A + (size_t)b * KDIM;
    *reinterpret_cast<short4*>(&row[i])              = make_short4(o1[0], o1[1], o1[2], o1[3]);
    *reinterpret_cast<short4*>(&row[IN_DIM + i])     = make_short4(o2[0], o2[1], o2[2], o2[3]);
    *reinterpret_cast<short4*>(&row[2 * IN_DIM + i]) = make_short4(o3[0], o3[1], o3[2], o3[3]);
}

// -------- prep: Bt [1024][3072] bf16 transpose + bias[o] = sum_i C[i][o][0] --------
__global__ __launch_bounds__(256) void prep_coeffs(const float* __restrict__ C,
                                                   short* __restrict__ Bt,
                                                   float* __restrict__ bias) {
    __shared__ short tile[3][32][33];
    __shared__ float red[8][32];
    const int i0 = blockIdx.x * 32;
    const int o0 = blockIdx.y * 32;
    const int t  = threadIdx.x;
    const int lo = t & 31;
    const int li = t >> 5;   // 0..7
    float part = 0.0f;
#pragma unroll
    for (int r = 0; r < 4; ++r) {
        int i = li + r * 8;
        const float4 c4 = *reinterpret_cast<const float4*>(
            &C[((size_t)(i0 + i) * OUT_DIM + (o0 + lo)) * 4]);
        tile[0][i][lo] = f2bf(c4.y);
        tile[1][i][lo] = f2bf(c4.z);
        tile[2][i][lo] = f2bf(c4.w);
        part += c4.x;
    }
    red[li][lo] = part;
    __syncthreads();
#pragma unroll
    for (int r = 0; r < 4; ++r) {
        int o = (t >> 5) + r * 8;
        int i = t & 31;
#pragma unroll
        for (int d = 0; d < 3; ++d)
            Bt[(size_t)(o0 + o) * KDIM + d * IN_DIM + (i0 + i)] = tile[d][i][o];
    }
    if (t < 32) {
        float s = 0.0f;
#pragma unroll
        for (int k = 0; k < 8; ++k) s += red[k][t];
        atomicAdd(&bias[o0 + t], s);
    }
}

// ---------------- GEMM: out = A * Bt^T + bias ----------------
__global__ __launch_bounds__(512, 2) void gemm_kan(
    const short* __restrict__ A,     // [BATCH][KDIM]
    const short* __restrict__ Bt,    // [OUT_DIM][KDIM]
    const float* __restrict__ bias,  // [OUT_DIM]
    float* __restrict__ out)         // [BATCH][OUT_DIM]
{
    extern __shared__ short lds[];   // 3 * LDS_TILE shorts = 144 KB

    const int tid  = threadIdx.x;
    const int lane = tid & 63;
    const int wid  = tid >> 6;   // 0..7
    const int wm   = wid >> 1;   // 0..3 (M)
    const int wn   = wid & 1;    // 0..1 (N)

    // XCD-aware swizzle: XCD k gets 32 consecutive logical blocks = 4 A-rows x 8 cols
    const int bid  = blockIdx.x;          // 0..255
    const int swz  = (bid & 7) * 32 + (bid >> 3);
    const int brow = (swz >> 3) * BM;
    const int bcol = (swz & 7) * BN;

    const int l15 = lane & 15, lh = lane >> 4, l7 = lane & 7;
    const int pc0 = lh ^ l7;            // phys chunk for kk=0
    const int pc1 = pc0 ^ 4;            // kk=1

    // fragment LDS offsets (shorts), swizzled: byte chunk ^= (row & 7)
    int aoff[4][2], boff[4][2];
#pragma unroll
    for (int mi = 0; mi < 4; ++mi) {
        int r = wm * 64 + mi * 16 + l15;
        aoff[mi][0] = r * 64 + pc0 * 8;
        aoff[mi][1] = r * 64 + pc1 * 8;
    }
#pragma unroll
    for (int ni = 0; ni < 4; ++ni) {
        int r = wn * 64 + ni * 16 + l15;
        boff[ni][0] = 16384 + r * 64 + pc0 * 8;
        boff[ni][1] = 16384 + r * 64 + pc1 * 8;
    }

    // staging geometry: thread tid handles row srow (+s*64), phys chunk tid&7
    const int srow   = tid >> 3;                    // 0..63
    const int schunk = (tid & 7) ^ (srow & 7);      // inverse-swizzled source chunk

    // stage one K-tile (6 x global_load_lds of 16B) into buffer b
#define STAGE(KT_TILE, B)                                                           \
    do {                                                                            \
        const int kt_ = (KT_TILE) * 64;                                             \
        short* lbase_ = lds + (B) * LDS_TILE;                                       \
        _Pragma("unroll")                                                           \
        for (int s_ = 0; s_ < 4; ++s_) {                                            \
            __builtin_amdgcn_global_load_lds(                                       \
                (const __attribute__((address_space(1))) void*)(                    \
                    A + (size_t)(brow + s_ * 64 + srow) * KDIM + kt_ + schunk * 8), \
                (__attribute__((address_space(3))) void*)(                          \
                    lbase_ + s_ * 4096 + tid * 8), 16, 0, 0);                       \
        }                                                                           \
        _Pragma("unroll")                                                           \
        for (int s_ = 0; s_ < 2; ++s_) {                                            \
            __builtin_amdgcn_global_load_lds(                                       \
                (const __attribute__((address_space(1))) void*)(                    \
                    Bt + (size_t)(bcol + s_ * 64 + srow) * KDIM + kt_ + schunk * 8),\
                (__attribute__((address_space(3))) void*)(                          \
                    lbase_ + 16384 + s_ * 4096 + tid * 8), 16, 0, 0);               \
        }                                                                           \
    } while (0)

    // prologue: bias -> acc, stage tiles 0 and 1
    f32x4 acc[4][4];
#pragma unroll
    for (int ni = 0; ni < 4; ++ni) {
        float bv = bias[bcol + wn * 64 + ni * 16 + l15];
#pragma unroll
        for (int mi = 0; mi < 4; ++mi)
            acc[mi][ni] = (f32x4){bv, bv, bv, bv};
    }
    STAGE(0, 0);
    STAGE(1, 1);
    asm volatile("s_waitcnt vmcnt(6)" ::: "memory");   // tile 0 landed
    __builtin_amdgcn_s_barrier();
    asm volatile("" ::: "memory");

    int buf = 0, sbuf = 2;
    for (int t = 0; t < NT; ++t) {
        if (t + 2 < NT) STAGE(t + 2, sbuf);            // issue prefetch early

        const short* Ab = lds + buf * LDS_TILE;
        bf16x8 af[4][2], bfr[4][2];
#pragma unroll
        for (int mi = 0; mi < 4; ++mi) {
            af[mi][0] = *reinterpret_cast<const bf16x8*>(Ab + aoff[mi][0]);
            af[mi][1] = *reinterpret_cast<const bf16x8*>(Ab + aoff[mi][1]);
        }
#pragma unroll
        for (int ni = 0; ni < 4; ++ni) {
            bfr[ni][0] = *reinterpret_cast<const bf16x8*>(Ab + boff[ni][0]);
            bfr[ni][1] = *reinterpret_cast<const bf16x8*>(Ab + boff[ni][1]);
        }
        __builtin_amdgcn_s_setprio(1);
#pragma unroll
        for (int kk = 0; kk < 2; ++kk)
#pragma unroll
            for (int mi = 0; mi < 4; ++mi)
#pragma unroll
                for (int ni = 0; ni < 4; ++ni)
                    acc[mi][ni] = __builtin_amdgcn_mfma_f32_16x16x32_bf16(
                        af[mi][kk], bfr[ni][kk], acc[mi][ni], 0, 0, 0);
        __builtin_amdgcn_s_setprio(0);

        // counted vmcnt: keep next prefetch (6 loads) in flight across barrier
        if (t + 2 < NT) { asm volatile("s_waitcnt vmcnt(6)" ::: "memory"); }
        else            { asm volatile("s_waitcnt vmcnt(0)" ::: "memory"); }
        __builtin_amdgcn_s_barrier();
        asm volatile("" ::: "memory");
        buf  = (buf  == 2) ? 0 : buf  + 1;
        sbuf = (sbuf == 2) ? 0 : sbuf + 1;
    }
#undef STAGE

    // epilogue: C/D layout col = lane&15, row = (lane>>4)*4 + reg
#pragma unroll
    for (int mi = 0; mi < 4; ++mi) {
#pragma unroll
        for (int r = 0; r < 4; ++r) {
            int row = brow + wm * 64 + mi * 16 + (lane >> 4) * 4 + r;
            float* orow = out + (size_t)row * OUT_DIM + bcol + wn * 64 + l15;
#pragma unroll
            for (int ni = 0; ni < 4; ++ni)
                orow[ni * 16] = acc[mi][ni][r];
        }
    }
}

extern "C" void kernel_launch(void* const* d_in, const int* in_sizes, int n_in,
                              void* d_out, int out_size, void* d_ws, size_t ws_size,
                              hipStream_t stream) {
    (void)in_sizes; (void)n_in; (void)out_size; (void)ws_size;
    const float* x      = (const float*)d_in[0];
    const float* coeffs = (const float*)d_in[1];
    float* out = (float*)d_out;

    char* ws = (char*)d_ws;
    short* A    = (short*)ws;                                        // 48 MB
    short* Bt   = (short*)(ws + (size_t)BATCH * KDIM * 2);           // 6 MB
    float* bias = (float*)(ws + (size_t)BATCH * KDIM * 2
                              + (size_t)OUT_DIM * KDIM * 2);         // 4 KB

    hipFuncSetAttribute((const void*)gemm_kan,
                        hipFuncAttributeMaxDynamicSharedMemorySize,
                        3 * LDS_TILE * (int)sizeof(short));

    hipMemsetAsync(bias, 0, OUT_DIM * sizeof(float), stream);
    hipLaunchKernelGGL(prep_basis, dim3(BATCH * IN_DIM / 4 / 256), dim3(256), 0, stream,
                       x, A);
    hipLaunchKernelGGL(prep_coeffs, dim3(IN_DIM / 32, OUT_DIM / 32), dim3(256), 0, stream,
                       coeffs, Bt, bias);
    hipLaunchKernelGGL(gemm_kan, dim3((BATCH / BM) * (OUT_DIM / BN)), dim3(512),
                       3 * LDS_TILE * sizeof(short), stream,
                       A, Bt, bias, out);
}